// Round 4
// baseline (151.679 us; speedup 1.0000x reference)
//
#include <hip/hip_runtime.h>
#include <hip/hip_bf16.h>
#include <math.h>

// Problem constants (B=1)
#define TT 2048
#define CC 768
#define NH 12
#define HDIM 64
#define QKVLD 2304   // 3*CC
#define NSEC 32      // TT/64

typedef short bf16x8 __attribute__((ext_vector_type(8)));
typedef float f32x4 __attribute__((ext_vector_type(4)));

#define MFMA16(a, b, c) __builtin_amdgcn_mfma_f32_16x16x32_bf16(a, b, c, 0, 0, 0)

__device__ __forceinline__ ushort f2bf(float f) {
  __hip_bfloat16 h = __float2bfloat16(f);
  return *reinterpret_cast<ushort*>(&h);
}

__device__ __forceinline__ void gload_lds16(const ushort* g, ushort* l) {
  __builtin_amdgcn_global_load_lds(
      (const __attribute__((address_space(1))) void*)g,
      (__attribute__((address_space(3))) void*)l, 16, 0, 0);
}

// ---------------------------------------------------------------------------
// f32 -> bf16 elementwise (x). 8 elems/thread.
// ---------------------------------------------------------------------------
__global__ __launch_bounds__(256) void convert_bf16_kernel(
    const float* __restrict__ in, ushort* __restrict__ out, int n) {
  int i = (blockIdx.x * 256 + threadIdx.x) * 8;
  if (i >= n) return;
  float4 a = *(const float4*)&in[i];
  float4 b = *(const float4*)&in[i + 4];
  bf16x8 o;
  o[0] = (short)f2bf(a.x); o[1] = (short)f2bf(a.y);
  o[2] = (short)f2bf(a.z); o[3] = (short)f2bf(a.w);
  o[4] = (short)f2bf(b.x); o[5] = (short)f2bf(b.y);
  o[6] = (short)f2bf(b.z); o[7] = (short)f2bf(b.w);
  *(bf16x8*)&out[i] = o;
}

// ---------------------------------------------------------------------------
// f32 [K][N] -> bf16 [N][K] transpose-convert. 64x64 tile, 256 threads.
// ---------------------------------------------------------------------------
__global__ __launch_bounds__(256) void transpose_bf16_kernel(
    const float* __restrict__ in, ushort* __restrict__ out, int K, int N) {
  __shared__ float tile[64][65];
  const int t = threadIdx.x;
  const int kb = blockIdx.y * 64, nb = blockIdx.x * 64;
  const int rg = t >> 4, cg = t & 15;
#pragma unroll
  for (int r = 0; r < 4; ++r) {
    float4 v = *(const float4*)&in[(size_t)(kb + rg * 4 + r) * N + nb + cg * 4];
    tile[rg * 4 + r][cg * 4 + 0] = v.x;
    tile[rg * 4 + r][cg * 4 + 1] = v.y;
    tile[rg * 4 + r][cg * 4 + 2] = v.z;
    tile[rg * 4 + r][cg * 4 + 3] = v.w;
  }
  __syncthreads();
#pragma unroll
  for (int r = 0; r < 4; ++r) {
    const int nl = rg * 4 + r;
    ushort4 o;
    o.x = f2bf(tile[cg * 4 + 0][nl]);
    o.y = f2bf(tile[cg * 4 + 1][nl]);
    o.z = f2bf(tile[cg * 4 + 2][nl]);
    o.w = f2bf(tile[cg * 4 + 3][nl]);
    *(ushort4*)&out[(size_t)(nb + nl) * K + kb + cg * 4] = o;
  }
}

// ---------------------------------------------------------------------------
// bf16 MFMA GEMM (B-transposed input): C[M,N] = A[M,K] @ Bt[N,K]^T + bias.
// 128x128 tile, BK=64, 4 waves, global_load_lds staging. Epilogues as before.
// ---------------------------------------------------------------------------
__global__ __launch_bounds__(256) void gemm_bt_bf16_kernel(
    const ushort* __restrict__ A, const ushort* __restrict__ Bt,
    const float* __restrict__ bias,
    ushort* __restrict__ qkvb, ushort* __restrict__ vT,
    float* __restrict__ Cf,
    int M, int N, int K) {
  __shared__ ushort As[128 * 64];
  __shared__ ushort Bs[128 * 64];
  const int tid = threadIdx.x;
  const int wid = tid >> 6, lane = tid & 63;
  const int lr = lane & 15, lg = lane >> 4;
  const int wr = wid >> 1, wc = wid & 1;
  const int bm = blockIdx.y * 128, bn = blockIdx.x * 128;

  f32x4 acc[4][4];
#pragma unroll
  for (int m = 0; m < 4; ++m)
#pragma unroll
    for (int n = 0; n < 4; ++n) acc[m][n] = (f32x4){0.f, 0.f, 0.f, 0.f};

  const int colu = (lane & 7) * 8;
  const int rowb = wid * 8 + (lane >> 3);

  for (int k0 = 0; k0 < K; k0 += 64) {
    __syncthreads();
#pragma unroll
    for (int i = 0; i < 4; ++i) {
      const int row = i * 32 + rowb;
      gload_lds16(A  + (size_t)(bm + row) * K + k0 + colu, &As[i * 2048 + wid * 512]);
      gload_lds16(Bt + (size_t)(bn + row) * K + k0 + colu, &Bs[i * 2048 + wid * 512]);
    }
    __syncthreads();
#pragma unroll
    for (int kk = 0; kk < 2; ++kk) {
      bf16x8 af[4], bfr[4];
#pragma unroll
      for (int m = 0; m < 4; ++m)
        af[m] = *(const bf16x8*)&As[(wr * 64 + m * 16 + lr) * 64 + kk * 32 + lg * 8];
#pragma unroll
      for (int n = 0; n < 4; ++n)
        bfr[n] = *(const bf16x8*)&Bs[(wc * 64 + n * 16 + lr) * 64 + kk * 32 + lg * 8];
#pragma unroll
      for (int m = 0; m < 4; ++m)
#pragma unroll
        for (int n = 0; n < 4; ++n)
          acc[m][n] = MFMA16(af[m], bfr[n], acc[m][n]);
    }
  }

  float bb[4];
#pragma unroll
  for (int n = 0; n < 4; ++n) bb[n] = bias[bn + wc * 64 + n * 16 + lr];

  if (Cf) {
#pragma unroll
    for (int m = 0; m < 4; ++m)
#pragma unroll
      for (int n = 0; n < 4; ++n)
#pragma unroll
        for (int r = 0; r < 4; ++r) {
          const int row = bm + wr * 64 + m * 16 + lg * 4 + r;
          const int col = bn + wc * 64 + n * 16 + lr;
          Cf[(size_t)row * N + col] = acc[m][n][r] + bb[n];
        }
  } else if (bn < 768) {          // Q (scaled by 1/8)
#pragma unroll
    for (int m = 0; m < 4; ++m)
#pragma unroll
      for (int n = 0; n < 4; ++n)
#pragma unroll
        for (int r = 0; r < 4; ++r) {
          const int row = bm + wr * 64 + m * 16 + lg * 4 + r;
          const int col = bn + wc * 64 + n * 16 + lr;
          qkvb[(size_t)row * QKVLD + col] = f2bf((acc[m][n][r] + bb[n]) * 0.125f);
        }
  } else if (bn < 1536) {         // K
#pragma unroll
    for (int m = 0; m < 4; ++m)
#pragma unroll
      for (int n = 0; n < 4; ++n)
#pragma unroll
        for (int r = 0; r < 4; ++r) {
          const int row = bm + wr * 64 + m * 16 + lg * 4 + r;
          const int col = bn + wc * 64 + n * 16 + lr;
          qkvb[(size_t)row * QKVLD + col] = f2bf(acc[m][n][r] + bb[n]);
        }
  } else {                        // V -> transposed
#pragma unroll
    for (int m = 0; m < 4; ++m)
#pragma unroll
      for (int n = 0; n < 4; ++n) {
        const int row0 = bm + wr * 64 + m * 16 + lg * 4;
        const int vrow = bn + wc * 64 + n * 16 + lr - 1536;
        ushort4 o;
        o.x = f2bf(acc[m][n][0] + bb[n]);
        o.y = f2bf(acc[m][n][1] + bb[n]);
        o.z = f2bf(acc[m][n][2] + bb[n]);
        o.w = f2bf(acc[m][n][3] + bb[n]);
        *(ushort4*)&vT[(size_t)vrow * TT + row0] = o;
      }
  }
}

// ---------------------------------------------------------------------------
// Landmark grouped-softmax attention, wave-split over key-sections.
// One block = (qsec, h); 4 waves; wave w handles sections s = w, w+4, ...
// Each wave: private K/V LDS buffer, full 64-query tile, private online
// state (mrun, dl, acc). No barriers in main loop (same-wave LDS ordering).
// Final 2-barrier merge: M = max m_w, D = sum cw*dl_w, y = sum cw*acc_w / D.
// ---------------------------------------------------------------------------
__global__ __launch_bounds__(256) void attn_mfma_kernel(
    const ushort* __restrict__ qkvb,  // [2048][2304] bf16 (Q pre-scaled)
    const ushort* __restrict__ vT,    // [768][2048]  bf16 (V transposed)
    ushort* __restrict__ y) {         // [2048][768]  bf16
  const int qsec = blockIdx.x, h = blockIdx.y;
  const int tid = threadIdx.x;
  const int w = tid >> 6, lane = tid & 63;
  const int lr = lane & 15, lg = lane >> 4;

  __shared__ ushort kv[4][2][64][72];   // [wave][K/V][row][col], 72 KiB
  __shared__ float stats[4][64][2];     // (m, dl) per wave per row

  // Q fragments for all 64 rows of this query section (A-frags, 4 row-tiles)
  bf16x8 qf[4][2];
#pragma unroll
  for (int mt = 0; mt < 4; ++mt) {
    const ushort* qp = qkvb + (size_t)(qsec * 64 + mt * 16 + lr) * QKVLD + h * HDIM + lg * 8;
    qf[mt][0] = *(const bf16x8*)qp;
    qf[mt][1] = *(const bf16x8*)(qp + 32);
  }

  f32x4 acc[4][4];
  float mrun[4][4], dl[4][4];
#pragma unroll
  for (int mt = 0; mt < 4; ++mt)
#pragma unroll
    for (int nt = 0; nt < 4; ++nt) acc[mt][nt] = (f32x4){0.f, 0.f, 0.f, 0.f};
#pragma unroll
  for (int mt = 0; mt < 4; ++mt)
#pragma unroll
    for (int r = 0; r < 4; ++r) { mrun[mt][r] = -INFINITY; dl[mt][r] = 0.f; }

  const int srow = lane >> 3;           // staging: 8 rows per iter
  const int scol = (lane & 7) * 8;
  ushort* Kb = &kv[w][0][0][0];
  ushort* Vb = &kv[w][1][0][0];

  for (int s = w; s <= qsec; s += 4) {
    // ---- stage section s: K rows + Vt rows into private buffers ----
#pragma unroll
    for (int i = 0; i < 8; ++i) {
      const int row = i * 8 + srow;
      *(bf16x8*)&Kb[row * 72 + scol] =
          *(const bf16x8*)(qkvb + (size_t)(s * 64 + row) * QKVLD + CC + h * HDIM + scol);
      *(bf16x8*)&Vb[row * 72 + scol] =
          *(const bf16x8*)(vT + (size_t)(h * HDIM + row) * TT + s * 64 + scol);
    }

    const bool cur = (s == qsec);

    // ---- K B-frags held across row-tiles ----
    bf16x8 kf[4][2];
#pragma unroll
    for (int nt = 0; nt < 4; ++nt) {
      kf[nt][0] = *(const bf16x8*)&Kb[(nt * 16 + lr) * 72 + lg * 8];
      kf[nt][1] = *(const bf16x8*)&Kb[(nt * 16 + lr) * 72 + 32 + lg * 8];
    }

#pragma unroll
    for (int mt = 0; mt < 4; ++mt) {
      // ---- S row-tile: 16 rows x 64 cols ----
      f32x4 s4[4];
#pragma unroll
      for (int nt = 0; nt < 4; ++nt) s4[nt] = (f32x4){0.f, 0.f, 0.f, 0.f};
#pragma unroll
      for (int nt = 0; nt < 4; ++nt) {
        s4[nt] = MFMA16(qf[mt][0], kf[nt][0], s4[nt]);
        s4[nt] = MFMA16(qf[mt][1], kf[nt][1], s4[nt]);
      }

      float lmv[4];
      if (!cur) {
#pragma unroll
        for (int r = 0; r < 4; ++r) lmv[r] = __shfl(s4[3][r], lane | 15);
        if (lr == 15) {
#pragma unroll
          for (int r = 0; r < 4; ++r) s4[3][r] = -INFINITY;
        }
      } else {
#pragma unroll
        for (int nt = 0; nt < 4; ++nt) {
          const int col = nt * 16 + lr;
#pragma unroll
          for (int r = 0; r < 4; ++r) {
            const int rowl = mt * 16 + lg * 4 + r;
            const int lim = rowl < 62 ? rowl : 62;
            if (col > lim) s4[nt][r] = -INFINITY;
          }
        }
      }

      float rmax[4];
#pragma unroll
      for (int r = 0; r < 4; ++r) {
        float v = fmaxf(fmaxf(s4[0][r], s4[1][r]), fmaxf(s4[2][r], s4[3][r]));
        v = fmaxf(v, __shfl_xor(v, 1));
        v = fmaxf(v, __shfl_xor(v, 2));
        v = fmaxf(v, __shfl_xor(v, 4));
        v = fmaxf(v, __shfl_xor(v, 8));
        rmax[r] = v;
      }

      float base[4];
      if (cur) {
#pragma unroll
        for (int r = 0; r < 4; ++r) {
          float mn = fmaxf(mrun[mt][r], rmax[r]);
          float sc = __expf(mrun[mt][r] - mn);
#pragma unroll
          for (int nt = 0; nt < 4; ++nt) acc[mt][nt][r] *= sc;
          dl[mt][r] *= sc;
          mrun[mt][r] = mn;
          base[r] = mn;
        }
      } else {
#pragma unroll
        for (int r = 0; r < 4; ++r) base[r] = rmax[r];
      }

      float dsum[4];
#pragma unroll
      for (int r = 0; r < 4; ++r) {
#pragma unroll
        for (int nt = 0; nt < 4; ++nt) s4[nt][r] = __expf(s4[nt][r] - base[r]);
        float v = s4[0][r] + s4[1][r] + s4[2][r] + s4[3][r];
        v += __shfl_xor(v, 1);
        v += __shfl_xor(v, 2);
        v += __shfl_xor(v, 4);
        v += __shfl_xor(v, 8);
        dsum[r] = v;
      }

      float coef[4];
      if (!cur) {
#pragma unroll
        for (int r = 0; r < 4; ++r) {
          float mn = fmaxf(mrun[mt][r], lmv[r]);
          float sc = __expf(mrun[mt][r] - mn);
          float el = __expf(lmv[r] - mn);
#pragma unroll
          for (int nt = 0; nt < 4; ++nt) acc[mt][nt][r] *= sc;
          dl[mt][r] = dl[mt][r] * sc + el;
          mrun[mt][r] = mn;
          coef[r] = el / dsum[r];
        }
      } else {
#pragma unroll
        for (int r = 0; r < 4; ++r) {
          coef[r] = 1.f;
          dl[mt][r] += dsum[r];
        }
      }

      // ---- P row-tile -> K buffer (K frags already consumed; reuse) ----
#pragma unroll
      for (int nt = 0; nt < 4; ++nt) {
#pragma unroll
        for (int r = 0; r < 4; ++r) {
          Kb[(mt * 16 + lg * 4 + r) * 72 + nt * 16 + lr] = f2bf(s4[nt][r] * coef[r]);
        }
      }
    }

    // ---- PV: acc += P @ V ----
    bf16x8 vf[4][2];
#pragma unroll
    for (int nt = 0; nt < 4; ++nt) {
      vf[nt][0] = *(const bf16x8*)&Vb[(nt * 16 + lr) * 72 + lg * 8];
      vf[nt][1] = *(const bf16x8*)&Vb[(nt * 16 + lr) * 72 + 32 + lg * 8];
    }
#pragma unroll
    for (int mt = 0; mt < 4; ++mt) {
      bf16x8 af0 = *(const bf16x8*)&Kb[(mt * 16 + lr) * 72 + lg * 8];
      bf16x8 af1 = *(const bf16x8*)&Kb[(mt * 16 + lr) * 72 + 32 + lg * 8];
#pragma unroll
      for (int nt = 0; nt < 4; ++nt) {
        acc[mt][nt] = MFMA16(af0, vf[nt][0], acc[mt][nt]);
        acc[mt][nt] = MFMA16(af1, vf[nt][1], acc[mt][nt]);
      }
    }
  }

  // ---- merge the 4 waves' partial states ----
  __syncthreads();   // everyone done with private K/V buffers

  float* aw = (float*)(&kv[0][0][0][0]) + w * (64 * 68);
#pragma unroll
  for (int mt = 0; mt < 4; ++mt)
#pragma unroll
    for (int nt = 0; nt < 4; ++nt)
#pragma unroll
      for (int r = 0; r < 4; ++r)
        aw[(mt * 16 + lg * 4 + r) * 68 + nt * 16 + lr] = acc[mt][nt][r];
  if (lr == 0) {
#pragma unroll
    for (int mt = 0; mt < 4; ++mt)
#pragma unroll
      for (int r = 0; r < 4; ++r) {
        stats[w][mt * 16 + lg * 4 + r][0] = mrun[mt][r];
        stats[w][mt * 16 + lg * 4 + r][1] = dl[mt][r];
      }
  }
  __syncthreads();

  // wave w outputs rows w*16..w*16+15; lane: row = w*16+lr, cols lg*16..+15
  {
    const int orow = w * 16 + lr;
    const int oc = lg * 16;
    float mw[4], dw[4];
#pragma unroll
    for (int ww = 0; ww < 4; ++ww) {
      mw[ww] = stats[ww][orow][0];
      dw[ww] = stats[ww][orow][1];
    }
    float M = fmaxf(fmaxf(mw[0], mw[1]), fmaxf(mw[2], mw[3]));
    float cw[4], D = 0.f;
#pragma unroll
    for (int ww = 0; ww < 4; ++ww) {
      cw[ww] = __expf(mw[ww] - M);
      D += cw[ww] * dw[ww];
    }
    const float invD = 1.f / D;
    const float* base = (const float*)(&kv[0][0][0][0]) + orow * 68 + oc;
    bf16x8 o0, o1;
#pragma unroll
    for (int j = 0; j < 8; ++j) {
      float v = 0.f;
#pragma unroll
      for (int ww = 0; ww < 4; ++ww) v += cw[ww] * base[ww * 4352 + j];
      o0[j] = (short)f2bf(v * invD);
    }
#pragma unroll
    for (int j = 0; j < 8; ++j) {
      float v = 0.f;
#pragma unroll
      for (int ww = 0; ww < 4; ++ww) v += cw[ww] * base[ww * 4352 + 8 + j];
      o1[j] = (short)f2bf(v * invD);
    }
    ushort* yp = y + (size_t)(qsec * 64 + orow) * CC + h * HDIM + oc;
    *(bf16x8*)yp = o0;
    *(bf16x8*)(yp + 8) = o1;
  }
}

// ---------------------------------------------------------------------------
extern "C" void kernel_launch(void* const* d_in, const int* in_sizes, int n_in,
                              void* d_out, int out_size, void* d_ws, size_t ws_size,
                              hipStream_t stream) {
  const float* x      = (const float*)d_in[0];
  // d_in[1] = is_mem: deterministic (t%64==63), recomputed in-kernel.
  const float* w_qkv  = (const float*)d_in[2];
  const float* b_qkv  = (const float*)d_in[3];
  const float* w_proj = (const float*)d_in[4];
  const float* b_proj = (const float*)d_in[5];
  float* out = (float*)d_out;

  ushort* xb     = (ushort*)d_ws;                    // 2048 x 768
  ushort* wqkvT  = xb + (size_t)TT * CC;             // 2304 x 768
  ushort* wprojT = wqkvT + (size_t)QKVLD * CC;       // 768 x 768
  ushort* qkvb   = wprojT + (size_t)CC * CC;         // 2048 x 2304
  ushort* vT     = qkvb + (size_t)TT * QKVLD;        // 768 x 2048
  ushort* y      = vT + (size_t)CC * TT;              // 2048 x 768

  convert_bf16_kernel<<<TT * CC / (256 * 8), 256, 0, stream>>>(x, xb, TT * CC);
  transpose_bf16_kernel<<<dim3(QKVLD / 64, CC / 64), 256, 0, stream>>>(
      w_qkv, wqkvT, CC, QKVLD);
  transpose_bf16_kernel<<<dim3(CC / 64, CC / 64), 256, 0, stream>>>(
      w_proj, wprojT, CC, CC);

  // qkv = xb @ wqkvT^T + b_qkv  (bf16 out, Q scaled, V transposed)
  gemm_bt_bf16_kernel<<<dim3(QKVLD / 128, TT / 128), 256, 0, stream>>>(
      xb, wqkvT, b_qkv, qkvb, vT, nullptr, TT, QKVLD, CC);

  attn_mfma_kernel<<<dim3(NSEC, NH), 256, 0, stream>>>(qkvb, vT, y);

  // out = y @ wprojT^T + b_proj  (f32 out)
  gemm_bt_bf16_kernel<<<dim3(CC / 128, TT / 128), 256, 0, stream>>>(
      y, wprojT, b_proj, nullptr, nullptr, out, TT, CC, CC);
}

// Round 5
// 124.191 us; speedup vs baseline: 1.2213x; 1.2213x over previous
//
#include <hip/hip_runtime.h>
#include <hip/hip_bf16.h>
#include <math.h>

// Problem constants (B=1)
#define TT 2048
#define CC 768
#define NH 12
#define HDIM 64
#define QKVLD 2304   // 3*CC
#define NSEC 32      // TT/64
#define NCHMAX 8     // max key-section chunks per query section (32/4)

typedef short bf16x8 __attribute__((ext_vector_type(8)));
typedef float f32x4 __attribute__((ext_vector_type(4)));

#define MFMA16(a, b, c) __builtin_amdgcn_mfma_f32_16x16x32_bf16(a, b, c, 0, 0, 0)

__device__ __forceinline__ ushort f2bf(float f) {
  __hip_bfloat16 h = __float2bfloat16(f);
  return *reinterpret_cast<ushort*>(&h);
}

__device__ __forceinline__ void gload_lds16(const ushort* g, ushort* l) {
  __builtin_amdgcn_global_load_lds(
      (const __attribute__((address_space(1))) void*)g,
      (__attribute__((address_space(3))) void*)l, 16, 0, 0);
}

// chunk_base(q) = sum_{j<q} (j/4+1)  -- prefix of per-qsec chunk counts
__device__ __forceinline__ int chunk_base(int q) {
  const int a = q >> 2, b = q & 3;
  return q + 2 * a * (a - 1) + a * b;
}

// ---------------------------------------------------------------------------
// f32 -> bf16 elementwise (x). 8 elems/thread.
// ---------------------------------------------------------------------------
__global__ __launch_bounds__(256) void convert_bf16_kernel(
    const float* __restrict__ in, ushort* __restrict__ out, int n) {
  int i = (blockIdx.x * 256 + threadIdx.x) * 8;
  if (i >= n) return;
  float4 a = *(const float4*)&in[i];
  float4 b = *(const float4*)&in[i + 4];
  bf16x8 o;
  o[0] = (short)f2bf(a.x); o[1] = (short)f2bf(a.y);
  o[2] = (short)f2bf(a.z); o[3] = (short)f2bf(a.w);
  o[4] = (short)f2bf(b.x); o[5] = (short)f2bf(b.y);
  o[6] = (short)f2bf(b.z); o[7] = (short)f2bf(b.w);
  *(bf16x8*)&out[i] = o;
}

// ---------------------------------------------------------------------------
// f32 [K][N] -> bf16 [N][K] transpose-convert. 64x64 tile, 256 threads.
// ---------------------------------------------------------------------------
__global__ __launch_bounds__(256) void transpose_bf16_kernel(
    const float* __restrict__ in, ushort* __restrict__ out, int K, int N) {
  __shared__ float tile[64][65];
  const int t = threadIdx.x;
  const int kb = blockIdx.y * 64, nb = blockIdx.x * 64;
  const int rg = t >> 4, cg = t & 15;
#pragma unroll
  for (int r = 0; r < 4; ++r) {
    float4 v = *(const float4*)&in[(size_t)(kb + rg * 4 + r) * N + nb + cg * 4];
    tile[rg * 4 + r][cg * 4 + 0] = v.x;
    tile[rg * 4 + r][cg * 4 + 1] = v.y;
    tile[rg * 4 + r][cg * 4 + 2] = v.z;
    tile[rg * 4 + r][cg * 4 + 3] = v.w;
  }
  __syncthreads();
#pragma unroll
  for (int r = 0; r < 4; ++r) {
    const int nl = rg * 4 + r;
    ushort4 o;
    o.x = f2bf(tile[cg * 4 + 0][nl]);
    o.y = f2bf(tile[cg * 4 + 1][nl]);
    o.z = f2bf(tile[cg * 4 + 2][nl]);
    o.w = f2bf(tile[cg * 4 + 3][nl]);
    *(ushort4*)&out[(size_t)(nb + nl) * K + kb + cg * 4] = o;
  }
}

// ---------------------------------------------------------------------------
// bf16 MFMA GEMM (B-transposed input): C[M,N] = A[M,K] @ Bt[N,K]^T + bias.
// 128x128 tile, BK=64, 4 waves, global_load_lds staging. Epilogues as before.
// ---------------------------------------------------------------------------
__global__ __launch_bounds__(256) void gemm_bt_bf16_kernel(
    const ushort* __restrict__ A, const ushort* __restrict__ Bt,
    const float* __restrict__ bias,
    ushort* __restrict__ qkvb, ushort* __restrict__ vT,
    float* __restrict__ Cf,
    int M, int N, int K) {
  __shared__ ushort As[128 * 64];
  __shared__ ushort Bs[128 * 64];
  const int tid = threadIdx.x;
  const int wid = tid >> 6, lane = tid & 63;
  const int lr = lane & 15, lg = lane >> 4;
  const int wr = wid >> 1, wc = wid & 1;
  const int bm = blockIdx.y * 128, bn = blockIdx.x * 128;

  f32x4 acc[4][4];
#pragma unroll
  for (int m = 0; m < 4; ++m)
#pragma unroll
    for (int n = 0; n < 4; ++n) acc[m][n] = (f32x4){0.f, 0.f, 0.f, 0.f};

  const int colu = (lane & 7) * 8;
  const int rowb = wid * 8 + (lane >> 3);

  for (int k0 = 0; k0 < K; k0 += 64) {
    __syncthreads();
#pragma unroll
    for (int i = 0; i < 4; ++i) {
      const int row = i * 32 + rowb;
      gload_lds16(A  + (size_t)(bm + row) * K + k0 + colu, &As[i * 2048 + wid * 512]);
      gload_lds16(Bt + (size_t)(bn + row) * K + k0 + colu, &Bs[i * 2048 + wid * 512]);
    }
    __syncthreads();
#pragma unroll
    for (int kk = 0; kk < 2; ++kk) {
      bf16x8 af[4], bfr[4];
#pragma unroll
      for (int m = 0; m < 4; ++m)
        af[m] = *(const bf16x8*)&As[(wr * 64 + m * 16 + lr) * 64 + kk * 32 + lg * 8];
#pragma unroll
      for (int n = 0; n < 4; ++n)
        bfr[n] = *(const bf16x8*)&Bs[(wc * 64 + n * 16 + lr) * 64 + kk * 32 + lg * 8];
#pragma unroll
      for (int m = 0; m < 4; ++m)
#pragma unroll
        for (int n = 0; n < 4; ++n)
          acc[m][n] = MFMA16(af[m], bfr[n], acc[m][n]);
    }
  }

  float bb[4];
#pragma unroll
  for (int n = 0; n < 4; ++n) bb[n] = bias[bn + wc * 64 + n * 16 + lr];

  if (Cf) {
#pragma unroll
    for (int m = 0; m < 4; ++m)
#pragma unroll
      for (int n = 0; n < 4; ++n)
#pragma unroll
        for (int r = 0; r < 4; ++r) {
          const int row = bm + wr * 64 + m * 16 + lg * 4 + r;
          const int col = bn + wc * 64 + n * 16 + lr;
          Cf[(size_t)row * N + col] = acc[m][n][r] + bb[n];
        }
  } else if (bn < 768) {          // Q (scaled by 1/8)
#pragma unroll
    for (int m = 0; m < 4; ++m)
#pragma unroll
      for (int n = 0; n < 4; ++n)
#pragma unroll
        for (int r = 0; r < 4; ++r) {
          const int row = bm + wr * 64 + m * 16 + lg * 4 + r;
          const int col = bn + wc * 64 + n * 16 + lr;
          qkvb[(size_t)row * QKVLD + col] = f2bf((acc[m][n][r] + bb[n]) * 0.125f);
        }
  } else if (bn < 1536) {         // K
#pragma unroll
    for (int m = 0; m < 4; ++m)
#pragma unroll
      for (int n = 0; n < 4; ++n)
#pragma unroll
        for (int r = 0; r < 4; ++r) {
          const int row = bm + wr * 64 + m * 16 + lg * 4 + r;
          const int col = bn + wc * 64 + n * 16 + lr;
          qkvb[(size_t)row * QKVLD + col] = f2bf(acc[m][n][r] + bb[n]);
        }
  } else {                        // V -> transposed
#pragma unroll
    for (int m = 0; m < 4; ++m)
#pragma unroll
      for (int n = 0; n < 4; ++n) {
        const int row0 = bm + wr * 64 + m * 16 + lg * 4;
        const int vrow = bn + wc * 64 + n * 16 + lr - 1536;
        ushort4 o;
        o.x = f2bf(acc[m][n][0] + bb[n]);
        o.y = f2bf(acc[m][n][1] + bb[n]);
        o.z = f2bf(acc[m][n][2] + bb[n]);
        o.w = f2bf(acc[m][n][3] + bb[n]);
        *(ushort4*)&vT[(size_t)vrow * TT + row0] = o;
      }
  }
}

// ---------------------------------------------------------------------------
// Landmark grouped-softmax attention, CHUNKED (flash-decoding style).
// Block = (chunk c, qsec, h): processes key-sections [4c, min(4c+3, qsec)],
// 4 waves x 16 query rows (the validated round-2 structure, VGPR ~72).
// Writes partial (acc 64x64 f32, per-row m & dl) to workspace; merge kernel
// combines. Uniform small work per block -> ~1728 active blocks, no tail.
// ---------------------------------------------------------------------------
__global__ __launch_bounds__(256) void attn_chunk_kernel(
    const ushort* __restrict__ qkvb,  // [2048][2304] bf16 (Q pre-scaled)
    const ushort* __restrict__ vT,    // [768][2048]  bf16 (V transposed)
    float* __restrict__ pacc,         // [slot][64][64]
    float* __restrict__ pstats) {     // [slot][64][2]  (m, dl)
  const int c = blockIdx.x, qsec = blockIdx.y, h = blockIdx.z;
  if (c * 4 > qsec) return;
  const int tid = threadIdx.x;
  const int wid = tid >> 6, lane = tid & 63;
  const int lr = lane & 15, lg = lane >> 4;

  __shared__ ushort Klds[64][72];
  __shared__ ushort Vtlds[64][72];
  __shared__ ushort Plds[64][72];

  const int qrow = qsec * 64 + wid * 16 + lr;
  const ushort* qp = qkvb + (size_t)qrow * QKVLD + h * HDIM + lg * 8;
  const bf16x8 qf0 = *(const bf16x8*)qp;
  const bf16x8 qf1 = *(const bf16x8*)(qp + 32);

  f32x4 accy[4];
  float mrun[4], dl[4];
#pragma unroll
  for (int nt = 0; nt < 4; ++nt) accy[nt] = (f32x4){0.f, 0.f, 0.f, 0.f};
#pragma unroll
  for (int r = 0; r < 4; ++r) { mrun[r] = -INFINITY; dl[r] = 0.f; }

  const int send = (c * 4 + 3 < qsec) ? c * 4 + 3 : qsec;
  for (int s = c * 4; s <= send; ++s) {
    __syncthreads();
    {
      const int kr = tid >> 2, c16 = (tid & 3) * 16;
      const ushort* ksrc = qkvb + (size_t)(s * 64 + kr) * QKVLD + CC + h * HDIM + c16;
      *(bf16x8*)&Klds[kr][c16]     = *(const bf16x8*)ksrc;
      *(bf16x8*)&Klds[kr][c16 + 8] = *(const bf16x8*)(ksrc + 8);
      const ushort* vsrc = vT + (size_t)(h * HDIM + kr) * TT + s * 64 + c16;
      *(bf16x8*)&Vtlds[kr][c16]     = *(const bf16x8*)vsrc;
      *(bf16x8*)&Vtlds[kr][c16 + 8] = *(const bf16x8*)(vsrc + 8);
    }
    __syncthreads();

    f32x4 sacc[4];
#pragma unroll
    for (int nt = 0; nt < 4; ++nt) sacc[nt] = (f32x4){0.f, 0.f, 0.f, 0.f};
#pragma unroll
    for (int nt = 0; nt < 4; ++nt) {
      bf16x8 kf = *(const bf16x8*)&Klds[nt * 16 + lr][lg * 8];
      sacc[nt] = MFMA16(qf0, kf, sacc[nt]);
    }
#pragma unroll
    for (int nt = 0; nt < 4; ++nt) {
      bf16x8 kf = *(const bf16x8*)&Klds[nt * 16 + lr][32 + lg * 8];
      sacc[nt] = MFMA16(qf1, kf, sacc[nt]);
    }

    const bool cur = (s == qsec);
    float lmv[4];
    if (!cur) {
#pragma unroll
      for (int r = 0; r < 4; ++r) lmv[r] = __shfl(sacc[3][r], lane | 15);
      if (lr == 15) {
#pragma unroll
        for (int r = 0; r < 4; ++r) sacc[3][r] = -INFINITY;
      }
    } else {
#pragma unroll
      for (int nt = 0; nt < 4; ++nt) {
        const int col = nt * 16 + lr;
#pragma unroll
        for (int r = 0; r < 4; ++r) {
          const int rowl = wid * 16 + lg * 4 + r;
          const int lim = rowl < 62 ? rowl : 62;
          if (col > lim) sacc[nt][r] = -INFINITY;
        }
      }
    }

    float rmax[4];
#pragma unroll
    for (int r = 0; r < 4; ++r) {
      float v = fmaxf(fmaxf(sacc[0][r], sacc[1][r]), fmaxf(sacc[2][r], sacc[3][r]));
      v = fmaxf(v, __shfl_xor(v, 1));
      v = fmaxf(v, __shfl_xor(v, 2));
      v = fmaxf(v, __shfl_xor(v, 4));
      v = fmaxf(v, __shfl_xor(v, 8));
      rmax[r] = v;
    }

    float base[4];
    if (cur) {
#pragma unroll
      for (int r = 0; r < 4; ++r) {
        float mn = fmaxf(mrun[r], rmax[r]);
        float sc = __expf(mrun[r] - mn);
#pragma unroll
        for (int nt = 0; nt < 4; ++nt) accy[nt][r] *= sc;
        dl[r] *= sc;
        mrun[r] = mn;
        base[r] = mn;
      }
    } else {
#pragma unroll
      for (int r = 0; r < 4; ++r) base[r] = rmax[r];
    }

    float dsum[4];
#pragma unroll
    for (int r = 0; r < 4; ++r) {
#pragma unroll
      for (int nt = 0; nt < 4; ++nt) sacc[nt][r] = __expf(sacc[nt][r] - base[r]);
      float v = sacc[0][r] + sacc[1][r] + sacc[2][r] + sacc[3][r];
      v += __shfl_xor(v, 1);
      v += __shfl_xor(v, 2);
      v += __shfl_xor(v, 4);
      v += __shfl_xor(v, 8);
      dsum[r] = v;
    }

    float coef[4];
    if (!cur) {
#pragma unroll
      for (int r = 0; r < 4; ++r) {
        float mn = fmaxf(mrun[r], lmv[r]);
        float sc = __expf(mrun[r] - mn);
        float el = __expf(lmv[r] - mn);
#pragma unroll
        for (int nt = 0; nt < 4; ++nt) accy[nt][r] *= sc;
        dl[r] = dl[r] * sc + el;
        mrun[r] = mn;
        coef[r] = el / dsum[r];
      }
    } else {
#pragma unroll
      for (int r = 0; r < 4; ++r) {
        coef[r] = 1.f;
        dl[r] += dsum[r];
      }
    }

#pragma unroll
    for (int nt = 0; nt < 4; ++nt) {
#pragma unroll
      for (int r = 0; r < 4; ++r) {
        Plds[wid * 16 + lg * 4 + r][nt * 16 + lr] = f2bf(sacc[nt][r] * coef[r]);
      }
    }

    {
      bf16x8 af0 = *(const bf16x8*)&Plds[wid * 16 + lr][lg * 8];
      bf16x8 af1 = *(const bf16x8*)&Plds[wid * 16 + lr][32 + lg * 8];
#pragma unroll
      for (int nt = 0; nt < 4; ++nt) {
        bf16x8 vf = *(const bf16x8*)&Vtlds[nt * 16 + lr][lg * 8];
        accy[nt] = MFMA16(af0, vf, accy[nt]);
      }
#pragma unroll
      for (int nt = 0; nt < 4; ++nt) {
        bf16x8 vf = *(const bf16x8*)&Vtlds[nt * 16 + lr][32 + lg * 8];
        accy[nt] = MFMA16(af1, vf, accy[nt]);
      }
    }
  }

  // ---- write partial state ----
  const int slot = (chunk_base(qsec) + c) * NH + h;
  float* ap = pacc + (size_t)slot * 4096;
#pragma unroll
  for (int nt = 0; nt < 4; ++nt)
#pragma unroll
    for (int r = 0; r < 4; ++r)
      ap[(wid * 16 + lg * 4 + r) * 64 + nt * 16 + lr] = accy[nt][r];
  if (lr == 0) {
    float* st = pstats + (size_t)slot * 128;
#pragma unroll
    for (int r = 0; r < 4; ++r) {
      st[(wid * 16 + lg * 4 + r) * 2 + 0] = mrun[r];
      st[(wid * 16 + lg * 4 + r) * 2 + 1] = dl[r];
    }
  }
}

// ---------------------------------------------------------------------------
// Merge partials: y[qsec*64+row][h*64+col] = sum_c cw_c*acc_c / D, bf16.
// Block = (qsec, h); thread handles 16 cols of one row.
// ---------------------------------------------------------------------------
__global__ __launch_bounds__(256) void attn_merge_kernel(
    const float* __restrict__ pacc, const float* __restrict__ pstats,
    ushort* __restrict__ y) {
  const int qsec = blockIdx.x, h = blockIdx.y;
  const int tid = threadIdx.x;
  const int nch = (qsec >> 2) + 1;
  const int sbase = chunk_base(qsec);
  const int row = tid >> 2, cg = (tid & 3) * 16;

  float M = -INFINITY;
  for (int cc = 0; cc < nch; ++cc)
    M = fmaxf(M, pstats[(size_t)((sbase + cc) * NH + h) * 128 + row * 2]);
  float D = 0.f;
  for (int cc = 0; cc < nch; ++cc) {
    const float* st = pstats + (size_t)((sbase + cc) * NH + h) * 128 + row * 2;
    D += __expf(st[0] - M) * st[1];
  }
  const float invD = 1.f / D;

  f32x4 v0 = {0, 0, 0, 0}, v1 = {0, 0, 0, 0}, v2 = {0, 0, 0, 0}, v3 = {0, 0, 0, 0};
  for (int cc = 0; cc < nch; ++cc) {
    const int slot = (sbase + cc) * NH + h;
    const float cw = __expf(pstats[(size_t)slot * 128 + row * 2] - M);
    const float* ap = pacc + (size_t)slot * 4096 + row * 64 + cg;
    v0 += cw * *(const f32x4*)&ap[0];
    v1 += cw * *(const f32x4*)&ap[4];
    v2 += cw * *(const f32x4*)&ap[8];
    v3 += cw * *(const f32x4*)&ap[12];
  }
  bf16x8 o0, o1;
#pragma unroll
  for (int j = 0; j < 4; ++j) {
    o0[j]     = (short)f2bf(v0[j] * invD);
    o0[j + 4] = (short)f2bf(v1[j] * invD);
    o1[j]     = (short)f2bf(v2[j] * invD);
    o1[j + 4] = (short)f2bf(v3[j] * invD);
  }
  ushort* yp = y + (size_t)(qsec * 64 + row) * CC + h * HDIM + cg;
  *(bf16x8*)yp = o0;
  *(bf16x8*)(yp + 8) = o1;
}

// ---------------------------------------------------------------------------
extern "C" void kernel_launch(void* const* d_in, const int* in_sizes, int n_in,
                              void* d_out, int out_size, void* d_ws, size_t ws_size,
                              hipStream_t stream) {
  const float* x      = (const float*)d_in[0];
  // d_in[1] = is_mem: deterministic (t%64==63), recomputed in-kernel.
  const float* w_qkv  = (const float*)d_in[2];
  const float* b_qkv  = (const float*)d_in[3];
  const float* w_proj = (const float*)d_in[4];
  const float* b_proj = (const float*)d_in[5];
  float* out = (float*)d_out;

  // ws layout (bf16 elems unless noted). partial region aliases xb/wqkvT
  // (both dead once the qkv GEMM completes; stream is serial).
  ushort* wprojT = (ushort*)d_ws;                     // 768 x 768
  ushort* qkvb   = wprojT + (size_t)CC * CC;          // 2048 x 2304
  ushort* vT     = qkvb + (size_t)TT * QKVLD;         // 768 x 2048
  ushort* y      = vT + (size_t)CC * TT;              // 2048 x 768
  float*  pacc   = (float*)(y + (size_t)TT * CC);     // 1728 x 4096 f32
  float*  pstats = pacc + (size_t)1728 * 4096;        // 1728 x 128 f32
  ushort* xb     = (ushort*)pacc;                     // alias: 2048 x 768
  ushort* wqkvT  = xb + (size_t)TT * CC;              // alias: 2304 x 768

  convert_bf16_kernel<<<TT * CC / (256 * 8), 256, 0, stream>>>(x, xb, TT * CC);
  transpose_bf16_kernel<<<dim3(QKVLD / 64, CC / 64), 256, 0, stream>>>(
      w_qkv, wqkvT, CC, QKVLD);
  transpose_bf16_kernel<<<dim3(CC / 64, CC / 64), 256, 0, stream>>>(
      w_proj, wprojT, CC, CC);

  // qkv = xb @ wqkvT^T + b_qkv  (bf16 out, Q scaled, V transposed)
  gemm_bt_bf16_kernel<<<dim3(QKVLD / 128, TT / 128), 256, 0, stream>>>(
      xb, wqkvT, b_qkv, qkvb, vT, nullptr, TT, QKVLD, CC);

  // chunked landmark attention + merge
  attn_chunk_kernel<<<dim3(NCHMAX, NSEC, NH), 256, 0, stream>>>(
      qkvb, vT, pacc, pstats);
  attn_merge_kernel<<<dim3(NSEC, NH), 256, 0, stream>>>(pacc, pstats, y);

  // out = y @ wprojT^T + b_proj  (f32 out)
  gemm_bt_bf16_kernel<<<dim3(CC / 128, TT / 128), 256, 0, stream>>>(
      y, wprojT, b_proj, nullptr, nullptr, out, TT, CC, CC);
}

// Round 6
// 103.359 us; speedup vs baseline: 1.4675x; 1.2016x over previous
//
#include <hip/hip_runtime.h>
#include <hip/hip_bf16.h>
#include <math.h>

// Problem constants (B=1)
#define TT 2048
#define CC 768
#define NH 12
#define HDIM 64
#define QKVLD 2304   // 3*CC
#define NSEC 32      // TT/64
#define NCHMAX 8     // max key-section chunks per query section (32/4)

typedef short bf16x8 __attribute__((ext_vector_type(8)));
typedef float f32x4 __attribute__((ext_vector_type(4)));

#define MFMA16(a, b, c) __builtin_amdgcn_mfma_f32_16x16x32_bf16(a, b, c, 0, 0, 0)

__device__ __forceinline__ ushort f2bf(float f) {
  __hip_bfloat16 h = __float2bfloat16(f);
  return *reinterpret_cast<ushort*>(&h);
}

__device__ __forceinline__ void gload_lds16(const ushort* g, ushort* l) {
  __builtin_amdgcn_global_load_lds(
      (const __attribute__((address_space(1))) void*)g,
      (__attribute__((address_space(3))) void*)l, 16, 0, 0);
}

// chunk_base(q) = sum_{j<q} (j/4+1)  -- prefix of per-qsec chunk counts
__device__ __forceinline__ int chunk_base(int q) {
  const int a = q >> 2, b = q & 3;
  return q + 2 * a * (a - 1) + a * b;
}

// ---------------------------------------------------------------------------
// f32 -> bf16 elementwise (x). 8 elems/thread.
// ---------------------------------------------------------------------------
__global__ __launch_bounds__(256) void convert_bf16_kernel(
    const float* __restrict__ in, ushort* __restrict__ out, int n) {
  int i = (blockIdx.x * 256 + threadIdx.x) * 8;
  if (i >= n) return;
  float4 a = *(const float4*)&in[i];
  float4 b = *(const float4*)&in[i + 4];
  bf16x8 o;
  o[0] = (short)f2bf(a.x); o[1] = (short)f2bf(a.y);
  o[2] = (short)f2bf(a.z); o[3] = (short)f2bf(a.w);
  o[4] = (short)f2bf(b.x); o[5] = (short)f2bf(b.y);
  o[6] = (short)f2bf(b.z); o[7] = (short)f2bf(b.w);
  *(bf16x8*)&out[i] = o;
}

// ---------------------------------------------------------------------------
// f32 [K][N] -> bf16 [N][K] transpose-convert. 64x64 tile, 256 threads.
// ---------------------------------------------------------------------------
__global__ __launch_bounds__(256) void transpose_bf16_kernel(
    const float* __restrict__ in, ushort* __restrict__ out, int K, int N) {
  __shared__ float tile[64][65];
  const int t = threadIdx.x;
  const int kb = blockIdx.y * 64, nb = blockIdx.x * 64;
  const int rg = t >> 4, cg = t & 15;
#pragma unroll
  for (int r = 0; r < 4; ++r) {
    float4 v = *(const float4*)&in[(size_t)(kb + rg * 4 + r) * N + nb + cg * 4];
    tile[rg * 4 + r][cg * 4 + 0] = v.x;
    tile[rg * 4 + r][cg * 4 + 1] = v.y;
    tile[rg * 4 + r][cg * 4 + 2] = v.z;
    tile[rg * 4 + r][cg * 4 + 3] = v.w;
  }
  __syncthreads();
#pragma unroll
  for (int r = 0; r < 4; ++r) {
    const int nl = rg * 4 + r;
    ushort4 o;
    o.x = f2bf(tile[cg * 4 + 0][nl]);
    o.y = f2bf(tile[cg * 4 + 1][nl]);
    o.z = f2bf(tile[cg * 4 + 2][nl]);
    o.w = f2bf(tile[cg * 4 + 3][nl]);
    *(ushort4*)&out[(size_t)(nb + nl) * K + kb + cg * 4] = o;
  }
}

// ---------------------------------------------------------------------------
// bf16 MFMA GEMM (B-transposed input): C[M,N] = A[M,K] @ Bt[N,K]^T + bias.
// 128x128 tile, BK=64, 4 waves, global_load_lds staging. Epilogues as before.
// ---------------------------------------------------------------------------
__global__ __launch_bounds__(256) void gemm_bt_bf16_kernel(
    const ushort* __restrict__ A, const ushort* __restrict__ Bt,
    const float* __restrict__ bias,
    ushort* __restrict__ qkvb, ushort* __restrict__ vT,
    float* __restrict__ Cf,
    int M, int N, int K) {
  __shared__ ushort As[128 * 64];
  __shared__ ushort Bs[128 * 64];
  const int tid = threadIdx.x;
  const int wid = tid >> 6, lane = tid & 63;
  const int lr = lane & 15, lg = lane >> 4;
  const int wr = wid >> 1, wc = wid & 1;
  const int bm = blockIdx.y * 128, bn = blockIdx.x * 128;

  f32x4 acc[4][4];
#pragma unroll
  for (int m = 0; m < 4; ++m)
#pragma unroll
    for (int n = 0; n < 4; ++n) acc[m][n] = (f32x4){0.f, 0.f, 0.f, 0.f};

  const int colu = (lane & 7) * 8;
  const int rowb = wid * 8 + (lane >> 3);

  for (int k0 = 0; k0 < K; k0 += 64) {
    __syncthreads();
#pragma unroll
    for (int i = 0; i < 4; ++i) {
      const int row = i * 32 + rowb;
      gload_lds16(A  + (size_t)(bm + row) * K + k0 + colu, &As[i * 2048 + wid * 512]);
      gload_lds16(Bt + (size_t)(bn + row) * K + k0 + colu, &Bs[i * 2048 + wid * 512]);
    }
    __syncthreads();
#pragma unroll
    for (int kk = 0; kk < 2; ++kk) {
      bf16x8 af[4], bfr[4];
#pragma unroll
      for (int m = 0; m < 4; ++m)
        af[m] = *(const bf16x8*)&As[(wr * 64 + m * 16 + lr) * 64 + kk * 32 + lg * 8];
#pragma unroll
      for (int n = 0; n < 4; ++n)
        bfr[n] = *(const bf16x8*)&Bs[(wc * 64 + n * 16 + lr) * 64 + kk * 32 + lg * 8];
#pragma unroll
      for (int m = 0; m < 4; ++m)
#pragma unroll
        for (int n = 0; n < 4; ++n)
          acc[m][n] = MFMA16(af[m], bfr[n], acc[m][n]);
    }
  }

  float bb[4];
#pragma unroll
  for (int n = 0; n < 4; ++n) bb[n] = bias[bn + wc * 64 + n * 16 + lr];

  if (Cf) {
#pragma unroll
    for (int m = 0; m < 4; ++m)
#pragma unroll
      for (int n = 0; n < 4; ++n)
#pragma unroll
        for (int r = 0; r < 4; ++r) {
          const int row = bm + wr * 64 + m * 16 + lg * 4 + r;
          const int col = bn + wc * 64 + n * 16 + lr;
          Cf[(size_t)row * N + col] = acc[m][n][r] + bb[n];
        }
  } else if (bn < 768) {          // Q (scaled by 1/8)
#pragma unroll
    for (int m = 0; m < 4; ++m)
#pragma unroll
      for (int n = 0; n < 4; ++n)
#pragma unroll
        for (int r = 0; r < 4; ++r) {
          const int row = bm + wr * 64 + m * 16 + lg * 4 + r;
          const int col = bn + wc * 64 + n * 16 + lr;
          qkvb[(size_t)row * QKVLD + col] = f2bf((acc[m][n][r] + bb[n]) * 0.125f);
        }
  } else if (bn < 1536) {         // K
#pragma unroll
    for (int m = 0; m < 4; ++m)
#pragma unroll
      for (int n = 0; n < 4; ++n)
#pragma unroll
        for (int r = 0; r < 4; ++r) {
          const int row = bm + wr * 64 + m * 16 + lg * 4 + r;
          const int col = bn + wc * 64 + n * 16 + lr;
          qkvb[(size_t)row * QKVLD + col] = f2bf(acc[m][n][r] + bb[n]);
        }
  } else {                        // V -> transposed
#pragma unroll
    for (int m = 0; m < 4; ++m)
#pragma unroll
      for (int n = 0; n < 4; ++n) {
        const int row0 = bm + wr * 64 + m * 16 + lg * 4;
        const int vrow = bn + wc * 64 + n * 16 + lr - 1536;
        ushort4 o;
        o.x = f2bf(acc[m][n][0] + bb[n]);
        o.y = f2bf(acc[m][n][1] + bb[n]);
        o.z = f2bf(acc[m][n][2] + bb[n]);
        o.w = f2bf(acc[m][n][3] + bb[n]);
        *(ushort4*)&vT[(size_t)vrow * TT + row0] = o;
      }
  }
}

// ---------------------------------------------------------------------------
// Landmark grouped-softmax attention, CHUNKED, swapped-QK (S^T = K @ Q^T).
// Block = (chunk c, qsec, h): key-sections [4c, min(4c+3,qsec)], 4 waves x
// 16 query rows. Lane (lr,lg) holds S^T values for query lr: keys
// nt*16+lg*4+r. Softmax is lane-local (15 fmax + 2 shfl); running (m,dl)
// are 2 scalar regs/lane. P packs as 4 x ds_write_b64. K/V staged via
// register prefetch (issue next section's loads before compute).
// ---------------------------------------------------------------------------
__global__ __launch_bounds__(256) void attn_chunk_kernel(
    const ushort* __restrict__ qkvb,  // [2048][2304] bf16 (Q pre-scaled)
    const ushort* __restrict__ vT,    // [768][2048]  bf16 (V transposed)
    float* __restrict__ pacc,         // [slot][64][64]
    float* __restrict__ pstats) {     // [slot][64][2]  (m, dl)
  const int c = blockIdx.x, qsec = blockIdx.y, h = blockIdx.z;
  if (c * 4 > qsec) return;
  const int tid = threadIdx.x;
  const int wid = tid >> 6, lane = tid & 63;
  const int lr = lane & 15, lg = lane >> 4;

  __shared__ ushort Klds[64][72];
  __shared__ ushort Vtlds[64][72];
  __shared__ ushort Plds[64][72];

  const int qloc = wid * 16 + lr;     // this lane's query row (softmax state)
  const ushort* qp = qkvb + (size_t)(qsec * 64 + qloc) * QKVLD + h * HDIM + lg * 8;
  const bf16x8 qf0 = *(const bf16x8*)qp;
  const bf16x8 qf1 = *(const bf16x8*)(qp + 32);

  f32x4 accy[4];
#pragma unroll
  for (int nt = 0; nt < 4; ++nt) accy[nt] = (f32x4){0.f, 0.f, 0.f, 0.f};
  float mrun = -INFINITY, dl = 0.f;

  // staging: wave w stages its own 16-row stripe; 4 lanes x 32 cols per row
  const int srow = wid * 16 + (lane >> 2);
  const int scol = (lane & 3) * 16;
  const ushort* kbase = qkvb + (size_t)srow * QKVLD + CC + h * HDIM + scol;
  const ushort* vbase = vT + (size_t)(h * HDIM + srow) * TT + scol;

  const int s0 = c * 4;
  const int send = (s0 + 3 < qsec) ? s0 + 3 : qsec;

  bf16x8 kr0, kr1, vr0, vr1;
  {
    const ushort* kp = kbase + (size_t)s0 * 64 * QKVLD;
    kr0 = *(const bf16x8*)kp;
    kr1 = *(const bf16x8*)(kp + 8);
    const ushort* vp = vbase + s0 * 64;
    vr0 = *(const bf16x8*)vp;
    vr1 = *(const bf16x8*)(vp + 8);
  }

  for (int s = s0; s <= send; ++s) {
    if (s > s0) __syncthreads();      // all waves done with K/V reads of s-1
    *(bf16x8*)&Klds[srow][scol]      = kr0;
    *(bf16x8*)&Klds[srow][scol + 8]  = kr1;
    *(bf16x8*)&Vtlds[srow][scol]     = vr0;
    *(bf16x8*)&Vtlds[srow][scol + 8] = vr1;
    if (s < send) {                   // prefetch next section (T14)
      const ushort* kp = kbase + (size_t)(s + 1) * 64 * QKVLD;
      kr0 = *(const bf16x8*)kp;
      kr1 = *(const bf16x8*)(kp + 8);
      const ushort* vp = vbase + (s + 1) * 64;
      vr0 = *(const bf16x8*)vp;
      vr1 = *(const bf16x8*)(vp + 8);
    }
    __syncthreads();                  // staging visible

    // ---- S^T = K @ Q^T: sacc[nt][r] = S[key=nt*16+lg*4+r][q=qloc] ----
    f32x4 sacc[4];
#pragma unroll
    for (int nt = 0; nt < 4; ++nt) sacc[nt] = (f32x4){0.f, 0.f, 0.f, 0.f};
#pragma unroll
    for (int nt = 0; nt < 4; ++nt) {
      bf16x8 kf = *(const bf16x8*)&Klds[nt * 16 + lr][lg * 8];
      sacc[nt] = MFMA16(kf, qf0, sacc[nt]);
    }
#pragma unroll
    for (int nt = 0; nt < 4; ++nt) {
      bf16x8 kf = *(const bf16x8*)&Klds[nt * 16 + lr][32 + lg * 8];
      sacc[nt] = MFMA16(kf, qf1, sacc[nt]);
    }

    const bool cur = (s == qsec);
    float lmv = 0.f;
    if (!cur) {
      // landmark = key 63 = (nt=3, lg=3, r=3); each lane fetches its query's
      lmv = __shfl(sacc[3][3], 48 + lr);
      if (lg == 3) sacc[3][3] = -INFINITY;   // exclude landmark from bucket s
    } else {
      // causal: key valid iff key <= min(qloc, 62)
      const int lim = qloc < 62 ? qloc : 62;
#pragma unroll
      for (int nt = 0; nt < 4; ++nt)
#pragma unroll
        for (int r = 0; r < 4; ++r)
          if (nt * 16 + lg * 4 + r > lim) sacc[nt][r] = -INFINITY;
    }

    // ---- per-query max: 15 in-lane fmax + 2 shfl ----
    float vmax = sacc[0][0];
#pragma unroll
    for (int nt = 0; nt < 4; ++nt)
#pragma unroll
      for (int r = 0; r < 4; ++r) vmax = fmaxf(vmax, sacc[nt][r]);
    vmax = fmaxf(vmax, __shfl_xor(vmax, 16));
    vmax = fmaxf(vmax, __shfl_xor(vmax, 32));

    float base_;
    if (cur) {
      float mn = fmaxf(mrun, vmax);
      float sc = __expf(mrun - mn);
#pragma unroll
      for (int r = 0; r < 4; ++r) {
        float scq = __shfl(sc, (lane & 48) | (lg * 4 + r));
#pragma unroll
        for (int nt = 0; nt < 4; ++nt) accy[nt][r] *= scq;
      }
      dl *= sc;
      mrun = mn;
      base_ = mn;
    } else {
      base_ = vmax;
    }

    // ---- exp + per-query sum (in-lane + 2 shfl) ----
    float ssum = 0.f;
#pragma unroll
    for (int nt = 0; nt < 4; ++nt)
#pragma unroll
      for (int r = 0; r < 4; ++r) {
        sacc[nt][r] = __expf(sacc[nt][r] - base_);
        ssum += sacc[nt][r];
      }
    ssum += __shfl_xor(ssum, 16);
    ssum += __shfl_xor(ssum, 32);

    float coef;
    if (!cur) {
      float mn = fmaxf(mrun, lmv);
      float sc = __expf(mrun - mn);
      float el = __expf(lmv - mn);
#pragma unroll
      for (int r = 0; r < 4; ++r) {
        float scq = __shfl(sc, (lane & 48) | (lg * 4 + r));
#pragma unroll
        for (int nt = 0; nt < 4; ++nt) accy[nt][r] *= scq;
      }
      dl = dl * sc + el;
      mrun = mn;
      coef = el / ssum;                // fold p63(lm_s)/d_s into P
    } else {
      coef = 1.f;
      dl += ssum;
    }

    // ---- P pack -> Plds[q=qloc][key]: 4 keys per b64 store ----
#pragma unroll
    for (int nt = 0; nt < 4; ++nt) {
      ushort4 o;
      o.x = f2bf(sacc[nt][0] * coef);
      o.y = f2bf(sacc[nt][1] * coef);
      o.z = f2bf(sacc[nt][2] * coef);
      o.w = f2bf(sacc[nt][3] * coef);
      *(ushort4*)&Plds[qloc][nt * 16 + lg * 4] = o;
    }

    // ---- PV: own-stripe P rows (wave-ordered, no barrier) ----
    {
      bf16x8 af0 = *(const bf16x8*)&Plds[qloc][lg * 8];
      bf16x8 af1 = *(const bf16x8*)&Plds[qloc][32 + lg * 8];
#pragma unroll
      for (int nt = 0; nt < 4; ++nt) {
        bf16x8 vf = *(const bf16x8*)&Vtlds[nt * 16 + lr][lg * 8];
        accy[nt] = MFMA16(af0, vf, accy[nt]);
      }
#pragma unroll
      for (int nt = 0; nt < 4; ++nt) {
        bf16x8 vf = *(const bf16x8*)&Vtlds[nt * 16 + lr][32 + lg * 8];
        accy[nt] = MFMA16(af1, vf, accy[nt]);
      }
    }
  }

  // ---- write partial state ----
  const int slot = (chunk_base(qsec) + c) * NH + h;
  float* ap = pacc + (size_t)slot * 4096;
#pragma unroll
  for (int nt = 0; nt < 4; ++nt)
#pragma unroll
    for (int r = 0; r < 4; ++r)
      ap[(wid * 16 + lg * 4 + r) * 64 + nt * 16 + lr] = accy[nt][r];
  if (lg == 0) {
    float* st = pstats + (size_t)slot * 128;
    st[(wid * 16 + lr) * 2 + 0] = mrun;
    st[(wid * 16 + lr) * 2 + 1] = dl;
  }
}

// ---------------------------------------------------------------------------
// Merge partials: y[qsec*64+row][h*64+col] = sum_c cw_c*acc_c / D, bf16.
// ---------------------------------------------------------------------------
__global__ __launch_bounds__(256) void attn_merge_kernel(
    const float* __restrict__ pacc, const float* __restrict__ pstats,
    ushort* __restrict__ y) {
  const int qsec = blockIdx.x, h = blockIdx.y;
  const int tid = threadIdx.x;
  const int nch = (qsec >> 2) + 1;
  const int sbase = chunk_base(qsec);
  const int row = tid >> 2, cg = (tid & 3) * 16;

  float M = -INFINITY;
  for (int cc = 0; cc < nch; ++cc)
    M = fmaxf(M, pstats[(size_t)((sbase + cc) * NH + h) * 128 + row * 2]);
  float D = 0.f;
  for (int cc = 0; cc < nch; ++cc) {
    const float* st = pstats + (size_t)((sbase + cc) * NH + h) * 128 + row * 2;
    D += __expf(st[0] - M) * st[1];
  }
  const float invD = 1.f / D;

  f32x4 v0 = {0, 0, 0, 0}, v1 = {0, 0, 0, 0}, v2 = {0, 0, 0, 0}, v3 = {0, 0, 0, 0};
  for (int cc = 0; cc < nch; ++cc) {
    const int slot = (sbase + cc) * NH + h;
    const float cw = __expf(pstats[(size_t)slot * 128 + row * 2] - M);
    const float* ap = pacc + (size_t)slot * 4096 + row * 64 + cg;
    v0 += cw * *(const f32x4*)&ap[0];
    v1 += cw * *(const f32x4*)&ap[4];
    v2 += cw * *(const f32x4*)&ap[8];
    v3 += cw * *(const f32x4*)&ap[12];
  }
  bf16x8 o0, o1;
#pragma unroll
  for (int j = 0; j < 4; ++j) {
    o0[j]     = (short)f2bf(v0[j] * invD);
    o0[j + 4] = (short)f2bf(v1[j] * invD);
    o1[j]     = (short)f2bf(v2[j] * invD);
    o1[j + 4] = (short)f2bf(v3[j] * invD);
  }
  ushort* yp = y + (size_t)(qsec * 64 + row) * CC + h * HDIM + cg;
  *(bf16x8*)yp = o0;
  *(bf16x8*)(yp + 8) = o1;
}

// ---------------------------------------------------------------------------
extern "C" void kernel_launch(void* const* d_in, const int* in_sizes, int n_in,
                              void* d_out, int out_size, void* d_ws, size_t ws_size,
                              hipStream_t stream) {
  const float* x      = (const float*)d_in[0];
  // d_in[1] = is_mem: deterministic (t%64==63), recomputed in-kernel.
  const float* w_qkv  = (const float*)d_in[2];
  const float* b_qkv  = (const float*)d_in[3];
  const float* w_proj = (const float*)d_in[4];
  const float* b_proj = (const float*)d_in[5];
  float* out = (float*)d_out;

  // ws layout (bf16 elems unless noted). partial region aliases xb/wqkvT
  // (both dead once the qkv GEMM completes; stream is serial).
  ushort* wprojT = (ushort*)d_ws;                     // 768 x 768
  ushort* qkvb   = wprojT + (size_t)CC * CC;          // 2048 x 2304
  ushort* vT     = qkvb + (size_t)TT * QKVLD;         // 768 x 2048
  ushort* y      = vT + (size_t)CC * TT;              // 2048 x 768
  float*  pacc   = (float*)(y + (size_t)TT * CC);     // 1728 x 4096 f32
  float*  pstats = pacc + (size_t)1728 * 4096;        // 1728 x 128 f32
  ushort* xb     = (ushort*)pacc;                     // alias: 2048 x 768
  ushort* wqkvT  = xb + (size_t)TT * CC;              // alias: 2304 x 768

  convert_bf16_kernel<<<TT * CC / (256 * 8), 256, 0, stream>>>(x, xb, TT * CC);
  transpose_bf16_kernel<<<dim3(QKVLD / 64, CC / 64), 256, 0, stream>>>(
      w_qkv, wqkvT, CC, QKVLD);
  transpose_bf16_kernel<<<dim3(CC / 64, CC / 64), 256, 0, stream>>>(
      w_proj, wprojT, CC, CC);

  // qkv = xb @ wqkvT^T + b_qkv  (bf16 out, Q scaled, V transposed)
  gemm_bt_bf16_kernel<<<dim3(QKVLD / 128, TT / 128), 256, 0, stream>>>(
      xb, wqkvT, b_qkv, qkvb, vT, nullptr, TT, QKVLD, CC);

  // chunked landmark attention + merge
  attn_chunk_kernel<<<dim3(NCHMAX, NSEC, NH), 256, 0, stream>>>(
      qkvb, vT, pacc, pstats);
  attn_merge_kernel<<<dim3(NSEC, NH), 256, 0, stream>>>(pacc, pstats, y);

  // out = y @ wprojT^T + b_proj  (f32 out)
  gemm_bt_bf16_kernel<<<dim3(CC / 128, TT / 128), 256, 0, stream>>>(
      y, wprojT, b_proj, nullptr, nullptr, out, TT, CC, CC);
}